// Round 3
// baseline (210.774 us; speedup 1.0000x reference)
//
#include <hip/hip_runtime.h>
#include <stdint.h>

namespace {

constexpr int kB = 256;
constexpr int kV = 128000;
constexpr int kSplit = 8;                       // V-chunks per row
constexpr int kBlk = 256;
constexpr int kChunk = kV / kSplit;             // 16000, divisible by 4

struct Part { float val; int idx; };

// JAX threefry2x32 with key = (0, 42)  [jax.random.key(42): hi=0, lo=42]
// Partitionable mode: bits[i] = o0 ^ o1 of threefry(x0=hi32(i)=0, x1=i).
// Verified bit-exact vs reference in R1/R2 (absmax = 0).
// __builtin_rotateleft32 guarantees v_alignbit_b32 (1 slot) per rotate.
__device__ __forceinline__ uint32_t threefry_bits(uint32_t x1) {
  constexpr uint32_t ks0 = 0u;
  constexpr uint32_t ks1 = 42u;
  constexpr uint32_t ks2 = 0x1BD11BDAu ^ ks0 ^ ks1;
  uint32_t x0 = ks0;          // 0 + ks0
  x1 += ks1;
#define TF_ROUND(r) { x0 += x1; x1 = __builtin_rotateleft32(x1, r); x1 ^= x0; }
  TF_ROUND(13) TF_ROUND(15) TF_ROUND(26) TF_ROUND(6)
  x0 += ks1; x1 += ks2 + 1u;
  TF_ROUND(17) TF_ROUND(29) TF_ROUND(16) TF_ROUND(24)
  x0 += ks2; x1 += ks0 + 2u;
  TF_ROUND(13) TF_ROUND(15) TF_ROUND(26) TF_ROUND(6)
  x0 += ks0; x1 += ks1 + 3u;
  TF_ROUND(17) TF_ROUND(29) TF_ROUND(16) TF_ROUND(24)
  x0 += ks1; x1 += ks2 + 4u;
  TF_ROUND(13) TF_ROUND(15) TF_ROUND(26) TF_ROUND(6)
  x0 += ks2; x1 += ks0 + 5u;
#undef TF_ROUND
  return x0 ^ x1;
}

// gumbel = -ln(-ln(u)), u = max(tiny, f + tiny), f = bitcast(bits>>9|0x3f800000)-1
// f >= 0 always, so f + tiny >= tiny: the fmax is a no-op and is dropped.
// Native v_log_f32 * -ln2 (verified bit-stable vs reference in R2, absmax 0).
__device__ __forceinline__ float gumbel_from_bits(uint32_t bits) {
  constexpr float kTiny = 1.17549435e-38f;  // FLT_MIN
  constexpr float kNegLn2 = -0.69314718055994530942f;
  float f = __uint_as_float((bits >> 9) | 0x3F800000u) - 1.0f;
  float u = f + kTiny;                            // == max(tiny, f + tiny)
  float y = __builtin_amdgcn_logf(u) * kNegLn2;   // -ln(u)  in (1.19e-7, 87.4)
  return __builtin_amdgcn_logf(y) * kNegLn2;      // -ln(-ln(u))
}

__global__ __launch_bounds__(kBlk) void sampler_partial(
    const float* __restrict__ logits, const float* __restrict__ temps,
    Part* __restrict__ parts) {
  const int r = blockIdx.x / kSplit;
  const int g = blockIdx.x % kSplit;
  const float t = temps[r];
  const bool greedy = (t == 0.0f);
  const int start = g * kChunk;
  const int end = start + kChunk;
  const float* __restrict__ row = logits + (size_t)r * kV;

  float best = -__builtin_inff();
  int bi = 0;

  if (greedy) {
    // pure argmax of raw logits, first-occurrence tie-break (strict >)
    for (int v = start + (int)threadIdx.x * 4; v + 3 < end; v += kBlk * 4) {
      float4 a = *reinterpret_cast<const float4*>(row + v);
      float la[4] = {a.x, a.y, a.z, a.w};
#pragma unroll
      for (int j = 0; j < 4; ++j) {
        if (la[j] > best) { best = la[j]; bi = v + j; }
      }
    }
  } else {
    // argmax(la/t + g) == argmax(la + t*g) for t > 0 (monotonic, real arith).
    // Software pipeline: next iteration's float4 is issued before processing
    // the current one, so one global load is always in flight per wave.
    int v = start + (int)threadIdx.x * 4;
    if (v + 3 < end) {
      float4 a = *reinterpret_cast<const float4*>(row + v);
      while (true) {
        const int vn = v + kBlk * 4;
        const bool have_next = (vn + 3 < end);
        float4 b;
        if (have_next) b = *reinterpret_cast<const float4*>(row + vn);

        float la[4] = {a.x, a.y, a.z, a.w};
        const uint32_t base = (uint32_t)(r * kV + v);  // flat index < 2^25
#pragma unroll
        for (int j = 0; j < 4; ++j) {
          float gb = gumbel_from_bits(threefry_bits(base + (uint32_t)j));
          float key = fmaf(t, gb, la[j]);
          if (key > best) { best = key; bi = v + j; }
        }

        if (!have_next) break;
        a = b; v = vn;
      }
    }
  }

  __shared__ float sv[kBlk];
  __shared__ int si[kBlk];
  sv[threadIdx.x] = best;
  si[threadIdx.x] = bi;
  __syncthreads();
  for (int s = kBlk / 2; s > 0; s >>= 1) {
    if ((int)threadIdx.x < s) {
      float ov = sv[threadIdx.x + s]; int oi = si[threadIdx.x + s];
      float mv = sv[threadIdx.x];     int mi = si[threadIdx.x];
      if (ov > mv || (ov == mv && oi < mi)) {
        sv[threadIdx.x] = ov; si[threadIdx.x] = oi;
      }
    }
    __syncthreads();
  }
  if (threadIdx.x == 0) {
    parts[r * kSplit + g].val = sv[0];
    parts[r * kSplit + g].idx = si[0];
  }
}

__global__ __launch_bounds__(kB) void sampler_final(
    const Part* __restrict__ parts, int* __restrict__ out) {
  const int r = threadIdx.x;
  if (r < kB) {
    float bv = -__builtin_inff();
    int bi = 0;
    for (int g = 0; g < kSplit; ++g) {
      Part p = parts[r * kSplit + g];
      if (p.val > bv || (p.val == bv && p.idx < bi)) { bv = p.val; bi = p.idx; }
    }
    out[r] = bi;
  }
}

}  // namespace

extern "C" void kernel_launch(void* const* d_in, const int* in_sizes, int n_in,
                              void* d_out, int out_size, void* d_ws, size_t ws_size,
                              hipStream_t stream) {
  const float* logits = (const float*)d_in[0];
  const float* temps = (const float*)d_in[1];
  int* out = (int*)d_out;
  Part* parts = (Part*)d_ws;  // kB * kSplit * 8 B = 16 KiB

  sampler_partial<<<dim3(kB * kSplit), dim3(kBlk), 0, stream>>>(logits, temps, parts);
  sampler_final<<<dim3(1), dim3(kB), 0, stream>>>(parts, out);
}

// Round 4
// 208.851 us; speedup vs baseline: 1.0092x; 1.0092x over previous
//
#include <hip/hip_runtime.h>
#include <stdint.h>

namespace {

constexpr int kB = 256;
constexpr int kV = 128000;
constexpr int kSplit = 25;                      // V-chunks per row
constexpr int kBlk = 256;
constexpr int kChunk = kV / kSplit;             // 5120 = 5 * (256*4)
constexpr int kIter = kChunk / (kBlk * 4);      // 5 — constant trip count

struct Part { float val; int idx; };

// JAX threefry2x32 with key = (0, 42)  [jax.random.key(42): hi=0, lo=42]
// Partitionable mode: bits[i] = o0 ^ o1 of threefry(x0=hi32(i)=0, x1=i).
// Bit-exact vs reference (absmax = 0, R1-R3).
__device__ __forceinline__ uint32_t threefry_bits(uint32_t x1) {
  constexpr uint32_t ks0 = 0u;
  constexpr uint32_t ks1 = 42u;
  constexpr uint32_t ks2 = 0x1BD11BDAu ^ ks0 ^ ks1;
  uint32_t x0 = ks0;          // 0 + ks0 (folds away)
  x1 += ks1;
#define TF_ROUND(r) { x0 += x1; x1 = __builtin_rotateleft32(x1, r); x1 ^= x0; }
  TF_ROUND(13) TF_ROUND(15) TF_ROUND(26) TF_ROUND(6)
  x0 += ks1; x1 += ks2 + 1u;
  TF_ROUND(17) TF_ROUND(29) TF_ROUND(16) TF_ROUND(24)
  x0 += ks2; x1 += ks0 + 2u;
  TF_ROUND(13) TF_ROUND(15) TF_ROUND(26) TF_ROUND(6)
  x0 += ks0; x1 += ks1 + 3u;
  TF_ROUND(17) TF_ROUND(29) TF_ROUND(16) TF_ROUND(24)
  x0 += ks1; x1 += ks2 + 4u;
  TF_ROUND(13) TF_ROUND(15) TF_ROUND(26) TF_ROUND(6)
  x0 += ks2; x1 += ks0 + 5u;
#undef TF_ROUND
  return x0 ^ x1;
}

// gumbel = -ln(-ln(u)), u = f + tiny (the reference fmax is a no-op since f>=0),
// f = bitcast(bits>>9 | 0x3f800000) - 1.  Native v_log_f32 * -ln2 (bit-stable
// vs reference across R2/R3 validations, absmax 0).
__device__ __forceinline__ float gumbel_from_bits(uint32_t bits) {
  constexpr float kTiny = 1.17549435e-38f;  // FLT_MIN
  constexpr float kNegLn2 = -0.69314718055994530942f;
  float f = __uint_as_float((bits >> 9) | 0x3F800000u) - 1.0f;
  float u = f + kTiny;
  float y = __builtin_amdgcn_logf(u) * kNegLn2;   // -ln(u)
  return __builtin_amdgcn_logf(y) * kNegLn2;      // -ln(-ln(u))
}

__global__ __launch_bounds__(kBlk) void sampler_partial(
    const float* __restrict__ logits, const float* __restrict__ temps,
    Part* __restrict__ parts) {
  const int r = blockIdx.x / kSplit;
  const int g = blockIdx.x % kSplit;
  const float t = temps[r];
  const int start = g * kChunk;
  const float* __restrict__ row = logits + (size_t)r * kV;
  const int tbase = start + (int)threadIdx.x * 4;

  // Load phase: kIter independent float4s issued back-to-back, one vmcnt
  // drain total. Constant trip count -> full unroll, no divergence.
  float4 a[kIter];
#pragma unroll
  for (int it = 0; it < kIter; ++it) {
    a[it] = *reinterpret_cast<const float4*>(row + tbase + it * kBlk * 4);
  }

  float best = -__builtin_inff();
  int bi = 0;

  if (t == 0.0f) {
    // greedy: pure argmax of raw logits, first-occurrence tie-break (strict >)
#pragma unroll
    for (int it = 0; it < kIter; ++it) {
      const int v = tbase + it * kBlk * 4;
      float la[4] = {a[it].x, a[it].y, a[it].z, a[it].w};
#pragma unroll
      for (int j = 0; j < 4; ++j) {
        if (la[j] > best) { best = la[j]; bi = v + j; }
      }
    }
  } else {
    // argmax(la/t + g) == argmax(la + t*g) for t > 0 (monotonic, real arith).
#pragma unroll
    for (int it = 0; it < kIter; ++it) {
      const int v = tbase + it * kBlk * 4;
      const uint32_t base = (uint32_t)(r * kV + v);  // flat index < 2^25
      float la[4] = {a[it].x, a[it].y, a[it].z, a[it].w};
#pragma unroll
      for (int j = 0; j < 4; ++j) {
        float gb = gumbel_from_bits(threefry_bits(base + (uint32_t)j));
        float key = fmaf(t, gb, la[j]);
        if (key > best) { best = key; bi = v + j; }
      }
    }
  }

  __shared__ float sv[kBlk];
  __shared__ int si[kBlk];
  sv[threadIdx.x] = best;
  si[threadIdx.x] = bi;
  __syncthreads();
  for (int s = kBlk / 2; s > 0; s >>= 1) {
    if ((int)threadIdx.x < s) {
      float ov = sv[threadIdx.x + s]; int oi = si[threadIdx.x + s];
      float mv = sv[threadIdx.x];     int mi = si[threadIdx.x];
      if (ov > mv || (ov == mv && oi < mi)) {
        sv[threadIdx.x] = ov; si[threadIdx.x] = oi;
      }
    }
    __syncthreads();
  }
  if (threadIdx.x == 0) {
    parts[r * kSplit + g].val = sv[0];
    parts[r * kSplit + g].idx = si[0];
  }
}

__global__ __launch_bounds__(kB) void sampler_final(
    const Part* __restrict__ parts, int* __restrict__ out) {
  const int r = threadIdx.x;
  if (r < kB) {
    float bv = -__builtin_inff();
    int bi = 0;
#pragma unroll
    for (int g = 0; g < kSplit; ++g) {
      Part p = parts[r * kSplit + g];
      // chunks scanned ascending: strict > + tie -> min idx
      if (p.val > bv || (p.val == bv && p.idx < bi)) { bv = p.val; bi = p.idx; }
    }
    out[r] = bi;
  }
}

}  // namespace

extern "C" void kernel_launch(void* const* d_in, const int* in_sizes, int n_in,
                              void* d_out, int out_size, void* d_ws, size_t ws_size,
                              hipStream_t stream) {
  const float* logits = (const float*)d_in[0];
  const float* temps = (const float*)d_in[1];
  int* out = (int*)d_out;
  Part* parts = (Part*)d_ws;  // kB * kSplit * 8 B = 51.2 KiB

  sampler_partial<<<dim3(kB * kSplit), dim3(kBlk), 0, stream>>>(logits, temps, parts);
  sampler_final<<<dim3(1), dim3(kB), 0, stream>>>(parts, out);
}

// Round 5
// 204.882 us; speedup vs baseline: 1.0288x; 1.0194x over previous
//
#include <hip/hip_runtime.h>
#include <stdint.h>

namespace {

constexpr int kB = 256;
constexpr int kV = 128000;
constexpr int kBlk = 256;
constexpr int kSplit = 25;                      // chunks per row
constexpr int kChunk = kV / kSplit;             // 5120 = 5 * (256*4)
constexpr int kIter = kChunk / (kBlk * 4);      // 5 float4 loads / chunk / thread
constexpr int kChunksPerBlk = 5;                // chunks owned by one block
constexpr int kSubs = kSplit / kChunksPerBlk;   // 5 blocks per row
// grid = kB * kSubs = 1280 blocks = 5 blocks/CU -> ALL co-resident (20 waves/CU)

struct Part { float val; int idx; };

// JAX threefry2x32, key = (0, 42). Partitionable mode: bits[i] = o0 ^ o1 of
// threefry(x0=hi32(i)=0, x1=i). Bit-exact vs reference (absmax = 0, R1-R4).
__device__ __forceinline__ uint32_t threefry_bits(uint32_t x1) {
  constexpr uint32_t ks0 = 0u;
  constexpr uint32_t ks1 = 42u;
  constexpr uint32_t ks2 = 0x1BD11BDAu ^ ks0 ^ ks1;
  uint32_t x0 = ks0;
  x1 += ks1;
#define TF_ROUND(r) { x0 += x1; x1 = __builtin_rotateleft32(x1, r); x1 ^= x0; }
  TF_ROUND(13) TF_ROUND(15) TF_ROUND(26) TF_ROUND(6)
  x0 += ks1; x1 += ks2 + 1u;
  TF_ROUND(17) TF_ROUND(29) TF_ROUND(16) TF_ROUND(24)
  x0 += ks2; x1 += ks0 + 2u;
  TF_ROUND(13) TF_ROUND(15) TF_ROUND(26) TF_ROUND(6)
  x0 += ks0; x1 += ks1 + 3u;
  TF_ROUND(17) TF_ROUND(29) TF_ROUND(16) TF_ROUND(24)
  x0 += ks1; x1 += ks2 + 4u;
  TF_ROUND(13) TF_ROUND(15) TF_ROUND(26) TF_ROUND(6)
  x0 += ks2; x1 += ks0 + 5u;
#undef TF_ROUND
  return x0 ^ x1;
}

// gumbel = -ln(-ln(f + tiny)), f = bitcast(bits>>9 | 0x3f800000) - 1.
// Native v_log_f32 * -ln2; bit-stable vs reference across R2-R4 (absmax 0).
__device__ __forceinline__ float gumbel_from_bits(uint32_t bits) {
  constexpr float kTiny = 1.17549435e-38f;  // FLT_MIN
  constexpr float kNegLn2 = -0.69314718055994530942f;
  float f = __uint_as_float((bits >> 9) | 0x3F800000u) - 1.0f;
  float u = f + kTiny;
  float y = __builtin_amdgcn_logf(u) * kNegLn2;   // -ln(u)
  return __builtin_amdgcn_logf(y) * kNegLn2;      // -ln(-ln(u))
}

__global__ __launch_bounds__(kBlk) void sampler_partial(
    const float* __restrict__ logits, const float* __restrict__ temps,
    Part* __restrict__ parts) {
  const int r = blockIdx.x / kSubs;
  const int s = blockIdx.x % kSubs;
  const float t = temps[r];
  const float* __restrict__ row = logits + (size_t)r * kV;
  const int tid4 = (int)threadIdx.x * 4;

  // Double-buffered register prefetch across the 5 chunks this block owns:
  // chunk k+1's 5 float4s are issued BEFORE chunk k's compute, so in steady
  // state no wave ever stalls on vmcnt (compute/chunk ~3800 cyc >> latency).
  float4 buf[2][kIter];

#define LOAD_CHUNK(k, p)                                                     \
  {                                                                          \
    const int cs_ = (s * kChunksPerBlk + (k)) * kChunk + tid4;               \
    _Pragma("unroll")                                                        \
    for (int i_ = 0; i_ < kIter; ++i_)                                       \
      buf[p][i_] = *reinterpret_cast<const float4*>(row + cs_ + i_ * kBlk * 4); \
  }

  float best = -__builtin_inff();
  int bi = 0;

  LOAD_CHUNK(0, 0)

  if (t == 0.0f) {
    // greedy: argmax of raw logits, first-occurrence tie-break (strict >,
    // per-thread scan order is strictly ascending in v).
#pragma unroll
    for (int k = 0; k < kChunksPerBlk; ++k) {
      if (k + 1 < kChunksPerBlk) LOAD_CHUNK(k + 1, (k + 1) & 1)
      const int cs = (s * kChunksPerBlk + k) * kChunk + tid4;
#pragma unroll
      for (int i = 0; i < kIter; ++i) {
        const int v = cs + i * kBlk * 4;
        float la[4] = {buf[k & 1][i].x, buf[k & 1][i].y,
                       buf[k & 1][i].z, buf[k & 1][i].w};
#pragma unroll
        for (int j = 0; j < 4; ++j) {
          if (la[j] > best) { best = la[j]; bi = v + j; }
        }
      }
    }
  } else {
    // argmax(la/t + g) == argmax(la + t*g) for t > 0 (monotonic, real arith).
#pragma unroll
    for (int k = 0; k < kChunksPerBlk; ++k) {
      if (k + 1 < kChunksPerBlk) LOAD_CHUNK(k + 1, (k + 1) & 1)
      const int cs = (s * kChunksPerBlk + k) * kChunk + tid4;
#pragma unroll
      for (int i = 0; i < kIter; ++i) {
        const int v = cs + i * kBlk * 4;
        const uint32_t base = (uint32_t)(r * kV + v);  // flat index < 2^25
        float la[4] = {buf[k & 1][i].x, buf[k & 1][i].y,
                       buf[k & 1][i].z, buf[k & 1][i].w};
#pragma unroll
        for (int j = 0; j < 4; ++j) {
          float gb = gumbel_from_bits(threefry_bits(base + (uint32_t)j));
          float key = fmaf(t, gb, la[j]);
          if (key > best) { best = key; bi = v + j; }
        }
      }
    }
  }
#undef LOAD_CHUNK

  // ONE reduction per block (was one per chunk): 1280 barriers total, not 6400.
  __shared__ float sv[kBlk];
  __shared__ int si[kBlk];
  sv[threadIdx.x] = best;
  si[threadIdx.x] = bi;
  __syncthreads();
  for (int st = kBlk / 2; st > 0; st >>= 1) {
    if ((int)threadIdx.x < st) {
      float ov = sv[threadIdx.x + st]; int oi = si[threadIdx.x + st];
      float mv = sv[threadIdx.x];      int mi = si[threadIdx.x];
      if (ov > mv || (ov == mv && oi < mi)) {
        sv[threadIdx.x] = ov; si[threadIdx.x] = oi;
      }
    }
    __syncthreads();
  }
  if (threadIdx.x == 0) {
    parts[r * kSubs + s].val = sv[0];
    parts[r * kSubs + s].idx = si[0];
  }
}

__global__ __launch_bounds__(kB) void sampler_final(
    const Part* __restrict__ parts, int* __restrict__ out) {
  const int r = threadIdx.x;
  if (r < kB) {
    float bv = -__builtin_inff();
    int bi = 0;
#pragma unroll
    for (int g = 0; g < kSubs; ++g) {
      Part p = parts[r * kSubs + g];
      // sub-blocks cover ascending index ranges: strict > + tie -> min idx
      if (p.val > bv || (p.val == bv && p.idx < bi)) { bv = p.val; bi = p.idx; }
    }
    out[r] = bi;
  }
}

}  // namespace

extern "C" void kernel_launch(void* const* d_in, const int* in_sizes, int n_in,
                              void* d_out, int out_size, void* d_ws, size_t ws_size,
                              hipStream_t stream) {
  const float* logits = (const float*)d_in[0];
  const float* temps = (const float*)d_in[1];
  int* out = (int*)d_out;
  Part* parts = (Part*)d_ws;  // kB * kSubs * 8 B = 10 KiB

  sampler_partial<<<dim3(kB * kSubs), dim3(kBlk), 0, stream>>>(logits, temps, parts);
  sampler_final<<<dim3(1), dim3(kB), 0, stream>>>(parts, out);
}